// Round 3
// baseline (145.241 us; speedup 1.0000x reference)
//
#include <hip/hip_runtime.h>
#include <cstdint>
#include <cstddef>

#define EPSV 1e-5f
typedef uint32_t u32;

// ---------------- stage A: conv1x1(q,k) + BN + ReLU + spatial partial-sum ----------------
// grid: 512 blocks = 128 n x 4 pixel-quarters (196 px, 1 px/thread), 256 threads.
// 64KB LDS W[c][o] (scale-folded), one pass over c with acc[64]/thread.
// Writes qk_part[(n*4+quarter)*64 + o]. No atomics, no pre-clear.
__global__ __launch_bounds__(256) void k_stageA(
    const float* __restrict__ x,
    const float* __restrict__ wq, const float* __restrict__ bq, const float* __restrict__ gq,
    const float* __restrict__ betaq, const float* __restrict__ mq, const float* __restrict__ vq,
    const float* __restrict__ wk, const float* __restrict__ bk, const float* __restrict__ gk,
    const float* __restrict__ betak, const float* __restrict__ mk, const float* __restrict__ vk,
    float* __restrict__ qk_part)
{
  __shared__ float Wsh[256*64];   // 64 KiB, Wsh[c*64+o]; reused as reduce buffer at the end
  __shared__ float Dsh[64];       // per-o epilogue constant (b-m)*s+beta

  const int tid = threadIdx.x;
  const int n = blockIdx.x >> 2;
  const int quarter = blockIdx.x & 3;

  for (int i = tid; i < 256*64; i += 256) {
    const int o = i & 63, c = i >> 6;
    float w, g, v;
    if (o < 32) { w = wq[o*256 + c];      g = gq[o];    v = vq[o]; }
    else        { w = wk[(o-32)*256 + c]; g = gk[o-32]; v = vk[o-32]; }
    Wsh[i] = w * (g * rsqrtf(v + EPSV));
  }
  if (tid < 64) {
    const int o = tid;
    float g,b,be,m,v;
    if (o < 32) { g=gq[o]; b=bq[o]; be=betaq[o]; m=mq[o]; v=vq[o]; }
    else        { g=gk[o-32]; b=bk[o-32]; be=betak[o-32]; m=mk[o-32]; v=vk[o-32]; }
    const float s = g * rsqrtf(v + EPSV);
    Dsh[o] = (b - m)*s + be;
  }
  __syncthreads();

  float acc[64];
#pragma unroll
  for (int o = 0; o < 64; ++o) acc[o] = 0.f;

  if (tid < 196) {
    const float* xp = x + (size_t)n*(256*784) + (size_t)(quarter*196 + tid);
    float xv = xp[0];
    for (int c = 0; c < 256; ++c) {
      const float xn = (c < 255) ? xp[(size_t)(c+1)*784] : 0.f;  // software pipeline
      const float* wrow = &Wsh[c*64];
#pragma unroll
      for (int o = 0; o < 64; ++o) acc[o] = fmaf(xv, wrow[o], acc[o]);
      xv = xn;
    }
#pragma unroll
    for (int o = 0; o < 64; ++o) acc[o] = fmaxf(acc[o] + Dsh[o], 0.f);
  }

  __syncthreads();   // all Wsh reads done -> reuse as reduction buffer
  const int wv = tid >> 6, lane = tid & 63;
#pragma unroll
  for (int o = 0; o < 64; ++o) {
    float v = acc[o];
    v += __shfl_down(v, 32, 64);
    v += __shfl_down(v, 16, 64);
    v += __shfl_down(v, 8, 64);
    v += __shfl_down(v, 4, 64);
    v += __shfl_down(v, 2, 64);
    v += __shfl_down(v, 1, 64);
    if (lane == 0) Wsh[wv*64 + o] = v;
  }
  __syncthreads();
  if (tid < 64) {
    qk_part[(size_t)blockIdx.x*64 + tid] =
        Wsh[tid] + Wsh[64+tid] + Wsh[128+tid] + Wsh[192+tid];
  }
}

// ---------------- stage B: per-group 8x8 attention + conv_inflate + BN + ReLU + sigmoid ----------------
// grid: 16 blocks (one per segment group of T=8), 256 threads
__global__ __launch_bounds__(256) void k_stageB(
    const float* __restrict__ qk_part,
    const float* __restrict__ wi, const float* __restrict__ bi, const float* __restrict__ gi,
    const float* __restrict__ betai, const float* __restrict__ mi, const float* __restrict__ vi,
    float* __restrict__ gate)
{
  __shared__ float ql[8][32], vl[8][32], attl[8][8], qul[8][32];
  const int tid = threadIdx.x;
  const int b = blockIdx.x;

  { // gather the 4 quarter-sums, convert to means
    const int i = tid >> 5, c = tid & 31;
    const int n = b*8 + i;
    float sq = 0.f, sv = 0.f;
#pragma unroll
    for (int qq = 0; qq < 4; ++qq) {
      sq += qk_part[(size_t)(n*4 + qq)*64 + c];
      sv += qk_part[(size_t)(n*4 + qq)*64 + 32 + c];
    }
    ql[i][c] = sq * (1.f/784.f);
    vl[i][c] = sv * (1.f/784.f);
  }
  __syncthreads();

  if (tid < 64) { // att[i][j] = -q_i.q_j ; softmax over i (axis 1) for fixed j
    const int i = tid >> 3, j = tid & 7;
    float d = 0.f;
#pragma unroll
    for (int c = 0; c < 32; ++c) d += ql[i][c]*ql[j][c];
    float a = -d;
    float m = a;                        // reduce over i: tid bits 3..5
    m = fmaxf(m, __shfl_xor(m, 8, 64));
    m = fmaxf(m, __shfl_xor(m, 16, 64));
    m = fmaxf(m, __shfl_xor(m, 32, 64));
    const float e = __expf(a - m);
    float s = e;
    s += __shfl_xor(s, 8, 64);
    s += __shfl_xor(s, 16, 64);
    s += __shfl_xor(s, 32, 64);
    attl[i][j] = e / s;
  }
  __syncthreads();

  { // q_upd[i][c] = sum_j att[i][j]*v[j][c] + v[i][c]
    const int i = tid >> 5, c = tid & 31;
    float acc = vl[i][c];
#pragma unroll
    for (int j = 0; j < 8; ++j) acc = fmaf(attl[i][j], vl[j][c], acc);
    qul[i][c] = acc;
  }
  __syncthreads();

  { // y[n,cout] = q_upd . wi[cout,:] (+bi), BN, ReLU, sigmoid
    const int cout = tid;
    float w[32];
#pragma unroll
    for (int k = 0; k < 32; ++k) w[k] = wi[cout*32 + k];
    const float s  = gi[cout] * rsqrtf(vi[cout] + EPSV);
    const float dd = (bi[cout] - mi[cout]) * s + betai[cout];
#pragma unroll
    for (int i = 0; i < 8; ++i) {
      float y = 0.f;
#pragma unroll
      for (int k = 0; k < 32; ++k) y = fmaf(qul[i][k], w[k], y);
      const float t = fmaxf(fmaf(y, s, dd), 0.f);
      gate[(size_t)(b*8 + i)*256 + cout] = 1.f / (1.f + __expf(-t));
    }
  }
}

// ---------------- stage C: out = gate[n,c] * x ----------------
// 784 f32/row = 196 float4 chunks -> a chunk never crosses a channel.
__global__ __launch_bounds__(256) void k_gateMul(
    const float* __restrict__ x, const float* __restrict__ gate, float* __restrict__ out)
{
  const u32 nchunk = 128u*256u*196u;   // 6,422,528
  const u32 stride = gridDim.x * 256u;
  for (u32 q = blockIdx.x*256u + threadIdx.x; q < nchunk; q += stride) {
    const u32 cn = q / 196u;           // n*256 + c
    const float g = gate[cn];
    const float4 v = reinterpret_cast<const float4*>(x)[q];
    float4 o4;
    o4.x = v.x * g; o4.y = v.y * g; o4.z = v.z * g; o4.w = v.w * g;
    reinterpret_cast<float4*>(out)[q] = o4;
  }
}

extern "C" void kernel_launch(void* const* d_in, const int* in_sizes, int n_in,
                              void* d_out, int out_size, void* d_ws, size_t ws_size,
                              hipStream_t stream) {
  const float* x    = (const float*)d_in[0];
  const float* wq   = (const float*)d_in[1];
  const float* bq   = (const float*)d_in[2];
  const float* gq   = (const float*)d_in[3];
  const float* betaq= (const float*)d_in[4];
  const float* mq   = (const float*)d_in[5];
  const float* vq   = (const float*)d_in[6];
  const float* wk   = (const float*)d_in[7];
  const float* bk   = (const float*)d_in[8];
  const float* gk   = (const float*)d_in[9];
  const float* betak= (const float*)d_in[10];
  const float* mk   = (const float*)d_in[11];
  const float* vk   = (const float*)d_in[12];
  const float* wi   = (const float*)d_in[13];
  const float* bi   = (const float*)d_in[14];
  const float* gi   = (const float*)d_in[15];
  const float* betai= (const float*)d_in[16];
  const float* mi   = (const float*)d_in[17];
  const float* vi   = (const float*)d_in[18];

  float* qk_part = (float*)d_ws;                                            // 512*64 f32 = 128KB
  float* gate    = (float*)((char*)d_ws + (size_t)512*64*sizeof(float));    // 128*256 f32 = 128KB

  k_stageA<<<512, 256, 0, stream>>>(x, wq,bq,gq,betaq,mq,vq, wk,bk,gk,betak,mk,vk, qk_part);
  k_stageB<<<16, 256, 0, stream>>>(qk_part, wi,bi,gi,betai,mi,vi, gate);
  k_gateMul<<<2048, 256, 0, stream>>>(x, gate, (float*)d_out);
}